// Round 1
// baseline (1422.257 us; speedup 1.0000x reference)
//
#include <hip/hip_runtime.h>
#include <math.h>

#define B_N 32
#define S_LEN 4096
#define NTOK (B_N * S_LEN)   // 131072
#define EMB 256
#define NCODE 512
#define WB_STRIDE 98304      // per-batch weight block (floats)

// ---- ws layout (floats) ----
constexpr size_t WS_W   = 0;          // 3,145,728 generated weights
constexpr size_t WS_CBN = 3145728;    // 512 codebook sq-norms
constexpr size_t WS_ACC = 3146240;    // 513: [0]=sse, [1..512]=hist
constexpr size_t WS_H0  = 3147264;    // 8,388,608 floats (h0 / h4)

// ---- out layout (floats) ----
constexpr size_t OUT_SCAL = 33554432; // loss, perplexity
constexpr size_t OUT_XR   = 33554434; // x_recon slot; reused for h1 / h3

// ================= weight generation =================
// W[b] = bw + (adapt[b] @ aw^T + ab), row r = o*in + i
__global__ __launch_bounds__(256)
void wgen_kernel(const float* __restrict__ bw, const float* __restrict__ aw,
                 const float* __restrict__ ab, const float* __restrict__ adapt,
                 float* __restrict__ wout, int rows, int loff)
{
    __shared__ float ad[B_N * 64];
    int tid = threadIdx.x;
    for (int i = tid; i < B_N * 64; i += 256) ad[i] = adapt[i];
    __syncthreads();
    int r = blockIdx.x * 256 + tid;
    if (r >= rows) return;
    float a[64];
    const float4* aw4 = reinterpret_cast<const float4*>(aw + (size_t)r * 64);
#pragma unroll
    for (int q = 0; q < 16; ++q) {
        float4 v = aw4[q];
        a[4*q] = v.x; a[4*q+1] = v.y; a[4*q+2] = v.z; a[4*q+3] = v.w;
    }
    float abr = ab[r], bwr = bw[r];
    for (int b2 = 0; b2 < B_N; ++b2) {
        const float* adp = &ad[b2 * 64];
        float s0 = 0.f, s1 = 0.f, s2 = 0.f, s3 = 0.f;
#pragma unroll
        for (int j = 0; j < 64; j += 4) {
            s0 += a[j]   * adp[j];
            s1 += a[j+1] * adp[j+1];
            s2 += a[j+2] * adp[j+2];
            s3 += a[j+3] * adp[j+3];
        }
        float s = ((s0 + s1) + (s2 + s3)) + abr;
        wout[(size_t)b2 * WB_STRIDE + loff + r] = bwr + s;
    }
}

// ================= codebook norms =================
__global__ __launch_bounds__(256)
void cbnorm_kernel(const float* __restrict__ cb, float* __restrict__ cbn)
{
    int c = blockIdx.x * 256 + threadIdx.x;
    if (c >= NCODE) return;
    const float4* c4 = reinterpret_cast<const float4*>(cb + (size_t)c * EMB);
    float s = 0.f;
#pragma unroll 8
    for (int q = 0; q < EMB / 4; ++q) {
        float4 v = c4[q];
        s += v.x*v.x + v.y*v.y + v.z*v.z + v.w*v.w;
    }
    cbn[c] = s;
}

// ================= liquid linear (batched GEMM, fused bias+act) =================
// ACT: 0 none, 1 relu, 2 sigmoid.  Global x/y accessed as float2 (h buffers in
// d_out's x_recon slot are only 8B-aligned).
template<int IN_F, int OUT_F, int OT, int TS, int ACT>
__global__ __launch_bounds__(256)
void liquid_gemm(const float* __restrict__ xg, const float* __restrict__ wsW,
                 const float* __restrict__ bbp, float* __restrict__ yg, int loff)
{
    constexpr int KC  = 32;
    constexpr int NKC = IN_F / KC;
    constexpr int OG  = OT / 4;        // threads along out
    constexpr int TG  = 256 / OG;      // threads along tokens
    constexpr int TT  = TS / TG;       // tokens per thread
    static_assert(TS * IN_F / 2 % 256 == 0, "");
    static_assert(OT * KC / 4 % 256 == 0, "");

    __shared__ float xT[IN_F][TS + 4]; // transposed, padded
    __shared__ float wc[KC][OT + 4];   // transposed chunk, padded

    const int tid = threadIdx.x;
    const int b   = blockIdx.y;
    const int s0  = blockIdx.x * TS;
    const int otb = blockIdx.z * OT;

    { // stage x tile (transpose)
        const float2* xg2 = reinterpret_cast<const float2*>(xg)
                          + (size_t)(b * S_LEN + s0) * (IN_F / 2);
        constexpr int TOT = TS * IN_F / 2;
#pragma unroll
        for (int it = 0; it < TOT / 256; ++it) {
            int idx = tid + it * 256;
            int t  = idx / (IN_F / 2);
            int k2 = idx % (IN_F / 2);
            float2 v = xg2[(size_t)t * (IN_F / 2) + k2];
            xT[2*k2][t]   = v.x;
            xT[2*k2+1][t] = v.y;
        }
    }

    const int og = tid % OG, tg = tid / OG;
    const int o0 = 4 * og, t0 = TT * tg;

    float acc[TT][4];
#pragma unroll
    for (int i = 0; i < TT; ++i)
#pragma unroll
        for (int j = 0; j < 4; ++j) acc[i][j] = 0.f;

    const float4* w4 = reinterpret_cast<const float4*>(
        wsW + (size_t)b * WB_STRIDE + loff + (size_t)otb * IN_F);

    for (int kc = 0; kc < NKC; ++kc) {
        __syncthreads();               // x staged / prev chunk consumed
        constexpr int WT = OT * KC / 4;
#pragma unroll
        for (int it = 0; it < WT / 256; ++it) {
            int idx = tid + it * 256;
            int o  = idx / (KC / 4);
            int k4 = idx % (KC / 4);
            float4 v = w4[(size_t)o * (IN_F / 4) + kc * (KC / 4) + k4];
            wc[4*k4+0][o] = v.x; wc[4*k4+1][o] = v.y;
            wc[4*k4+2][o] = v.z; wc[4*k4+3][o] = v.w;
        }
        __syncthreads();
        const int kb = kc * KC;
#pragma unroll 4
        for (int kk = 0; kk < KC; ++kk) {
            float xv[TT];
#pragma unroll
            for (int u = 0; u < TT / 4; ++u) {
                float4 t4 = *reinterpret_cast<const float4*>(&xT[kb + kk][t0 + 4*u]);
                xv[4*u] = t4.x; xv[4*u+1] = t4.y; xv[4*u+2] = t4.z; xv[4*u+3] = t4.w;
            }
            float4 wv = *reinterpret_cast<const float4*>(&wc[kk][o0]);
#pragma unroll
            for (int i = 0; i < TT; ++i) {
                acc[i][0] += xv[i] * wv.x;
                acc[i][1] += xv[i] * wv.y;
                acc[i][2] += xv[i] * wv.z;
                acc[i][3] += xv[i] * wv.w;
            }
        }
    }

    float4 bbv = *reinterpret_cast<const float4*>(&bbp[otb + o0]);
    float bba[4] = {bbv.x, bbv.y, bbv.z, bbv.w};
    float2* yg2 = reinterpret_cast<float2*>(yg);
#pragma unroll
    for (int i = 0; i < TT; ++i) {
        float r[4];
#pragma unroll
        for (int j = 0; j < 4; ++j) {
            float v = acc[i][j] + bba[j];
            if (ACT == 1)      v = fmaxf(v, 0.f);
            else if (ACT == 2) v = 1.0f / (1.0f + expf(-v));
            r[j] = v;
        }
        size_t row = ((size_t)b * S_LEN + s0 + t0 + i) * OUT_F + otb + o0;
        yg2[row / 2]     = make_float2(r[0], r[1]);
        yg2[row / 2 + 1] = make_float2(r[2], r[3]);
    }
}

// ================= vector quantize (in-place on z buffer) =================
// dist = (||z||^2 + ||e||^2) - 2*z.e ; argmin with first-index tie-break;
// writes z + (q - z); accumulates sse and histogram.
__global__ __launch_bounds__(256)
void vq_kernel(float* __restrict__ zq, const float* __restrict__ cb,
               const float* __restrict__ cbn, float* __restrict__ acc)
{
    __shared__ float zT[EMB][36];   // 32 tokens, transposed, padded
    __shared__ float cbT[32][132];  // 128 codes x 32 k, transposed, padded
    __shared__ float zn[32];
    __shared__ float rv[1024];
    __shared__ int   ri[1024];
    __shared__ int   bidx[32];

    const int tid  = threadIdx.x;
    const int tok0 = blockIdx.x * 32;

    { // stage z transposed
        const float4* z4 = reinterpret_cast<const float4*>(zq) + (size_t)tok0 * (EMB / 4);
#pragma unroll
        for (int it = 0; it < 8; ++it) {
            int idx = tid + it * 256;       // 0..2047
            int t = idx >> 6, k4 = idx & 63;
            float4 v = z4[(size_t)t * 64 + k4];
            zT[4*k4+0][t] = v.x; zT[4*k4+1][t] = v.y;
            zT[4*k4+2][t] = v.z; zT[4*k4+3][t] = v.w;
        }
    }
    __syncthreads();
    { // ||z||^2 per token (8-chunk parallel partials)
        int t = tid & 31, ch = tid >> 5;
        float s = 0.f;
        for (int k = ch * 32; k < ch * 32 + 32; ++k) { float v = zT[k][t]; s += v * v; }
        rv[ch * 32 + t] = s;
    }
    __syncthreads();
    if (tid < 32) {
        float s = 0.f;
#pragma unroll
        for (int ch = 0; ch < 8; ++ch) s += rv[ch * 32 + tid];
        zn[tid] = s;
    }
    __syncthreads();

    const int og = tid & 31, tg = tid >> 5;
    const int o0 = 4 * og, t0 = 4 * tg;
    float znv[4];
#pragma unroll
    for (int i = 0; i < 4; ++i) znv[i] = zn[t0 + i];

    float mv[4] = {1e30f, 1e30f, 1e30f, 1e30f};
    int   mi[4] = {0, 0, 0, 0};

    for (int cblk = 0; cblk < 4; ++cblk) {
        const int c_base = cblk * 128;
        float dot[4][4] = {};
        for (int kc = 0; kc < 8; ++kc) {
            __syncthreads();
#pragma unroll
            for (int it = 0; it < 4; ++it) {
                int idx = tid + it * 256;   // 0..1023
                int c = idx >> 3, k4 = idx & 7;
                const float4* cb4 = reinterpret_cast<const float4*>(cb);
                float4 v = cb4[(size_t)(c_base + c) * 64 + kc * 8 + k4];
                cbT[4*k4+0][c] = v.x; cbT[4*k4+1][c] = v.y;
                cbT[4*k4+2][c] = v.z; cbT[4*k4+3][c] = v.w;
            }
            __syncthreads();
            const int kb = kc * 32;
#pragma unroll 8
            for (int kk = 0; kk < 32; ++kk) {
                float4 zv = *reinterpret_cast<const float4*>(&zT[kb + kk][t0]);
                float4 cv = *reinterpret_cast<const float4*>(&cbT[kk][o0]);
                float za[4] = {zv.x, zv.y, zv.z, zv.w};
#pragma unroll
                for (int i = 0; i < 4; ++i) {
                    dot[i][0] += za[i] * cv.x;
                    dot[i][1] += za[i] * cv.y;
                    dot[i][2] += za[i] * cv.z;
                    dot[i][3] += za[i] * cv.w;
                }
            }
        }
        float4 cnv = *reinterpret_cast<const float4*>(&cbn[c_base + o0]);
        float cna[4] = {cnv.x, cnv.y, cnv.z, cnv.w};
#pragma unroll
        for (int j = 0; j < 4; ++j) {
            int c = c_base + o0 + j;    // ascending within thread
#pragma unroll
            for (int i = 0; i < 4; ++i) {
                float t1 = znv[i] + cna[j];
                float d  = t1 - 2.0f * dot[i][j];
                if (d < mv[i]) { mv[i] = d; mi[i] = c; }
            }
        }
    }
    __syncthreads();
#pragma unroll
    for (int i = 0; i < 4; ++i) {
        rv[(t0 + i) * 32 + og] = mv[i];
        ri[(t0 + i) * 32 + og] = mi[i];
    }
    __syncthreads();
    if (tid < 32) { // lexicographic (val, idx) min == numpy first-index argmin
        float bv = rv[tid * 32]; int bi = ri[tid * 32];
        for (int g = 1; g < 32; ++g) {
            float v = rv[tid * 32 + g]; int ii = ri[tid * 32 + g];
            if (v < bv || (v == bv && ii < bi)) { bv = v; bi = ii; }
        }
        bidx[tid] = bi;
    }
    __syncthreads();
    if (tid < 32) atomicAdd(&acc[1 + bidx[tid]], 1.0f);

    float lsse = 0.f;
    for (int idx = tid; idx < 32 * EMB; idx += 256) {
        int t = idx >> 8, i = idx & 255;
        float q  = cb[(size_t)bidx[t] * EMB + i];
        float zv = zT[i][t];
        float df = q - zv;
        lsse += df * df;
        zq[(size_t)(tok0 + t) * EMB + i] = zv + (q - zv);  // straight-through, ref-exact
    }
    __syncthreads();
    rv[tid] = lsse;
    __syncthreads();
    for (int s = 128; s > 0; s >>= 1) {
        if (tid < s) rv[tid] += rv[tid + s];
        __syncthreads();
    }
    if (tid == 0) atomicAdd(&acc[0], rv[0]);
}

// ================= finalize scalars =================
__global__ __launch_bounds__(512)
void finalize_kernel(const float* __restrict__ acc, float* __restrict__ out_scal)
{
    __shared__ float red[512];
    int tid = threadIdx.x;
    float p = acc[1 + tid] * (1.0f / (float)NTOK);
    red[tid] = p * logf(p + 1e-10f);
    __syncthreads();
    for (int s = 256; s > 0; s >>= 1) {
        if (tid < s) red[tid] += red[tid + s];
        __syncthreads();
    }
    if (tid == 0) {
        out_scal[0] = 1.25f * (acc[0] * (1.0f / 33554432.0f)); // q_latent + 0.25*e_latent
        out_scal[1] = expf(-red[0]);
    }
}

// ================= launch =================
extern "C" void kernel_launch(void* const* d_in, const int* in_sizes, int n_in,
                              void* d_out, int out_size, void* d_ws, size_t ws_size,
                              hipStream_t stream)
{
    (void)in_sizes; (void)n_in; (void)out_size; (void)ws_size;
    const float* x     = (const float*)d_in[0];
    const float* adapt = (const float*)d_in[1];
    const float* bw[6]  = {(const float*)d_in[2],  (const float*)d_in[6],  (const float*)d_in[10],
                           (const float*)d_in[14], (const float*)d_in[18], (const float*)d_in[22]};
    const float* bbp[6] = {(const float*)d_in[3],  (const float*)d_in[7],  (const float*)d_in[11],
                           (const float*)d_in[15], (const float*)d_in[19], (const float*)d_in[23]};
    const float* aw[6]  = {(const float*)d_in[4],  (const float*)d_in[8],  (const float*)d_in[12],
                           (const float*)d_in[16], (const float*)d_in[20], (const float*)d_in[24]};
    const float* ab[6]  = {(const float*)d_in[5],  (const float*)d_in[9],  (const float*)d_in[13],
                           (const float*)d_in[17], (const float*)d_in[21], (const float*)d_in[25]};
    const float* cb = (const float*)d_in[26];

    float* ws   = (float*)d_ws;
    float* wsW  = ws + WS_W;
    float* cbn  = ws + WS_CBN;
    float* acc  = ws + WS_ACC;
    float* h0   = ws + WS_H0;          // h0 / h4

    float* out  = (float*)d_out;
    float* zq   = out;                 // z_e -> z_q (in place)
    float* scal = out + OUT_SCAL;
    float* h1   = out + OUT_XR;        // h1 / h3 / x_recon share this slot

    hipMemsetAsync(acc, 0, 513 * sizeof(float), stream);

    const int rows[6] = {8192, 8192, 32768, 32768, 8192, 8192};
    const int loff[6] = {0, 8192, 16384, 49152, 81920, 90112};
    for (int l = 0; l < 6; ++l)
        wgen_kernel<<<rows[l] / 256, 256, 0, stream>>>(bw[l], aw[l], ab[l], adapt,
                                                       wsW, rows[l], loff[l]);
    cbnorm_kernel<<<2, 256, 0, stream>>>(cb, cbn);

    // encoder
    liquid_gemm<128,  64,  64, 64, 1><<<dim3(64, 32, 1), 256, 0, stream>>>(x,  wsW, bbp[0], h0, 0);
    liquid_gemm< 64, 128, 128, 64, 1><<<dim3(64, 32, 1), 256, 0, stream>>>(h0, wsW, bbp[1], h1, 8192);
    liquid_gemm<128, 256, 128, 64, 0><<<dim3(64, 32, 2), 256, 0, stream>>>(h1, wsW, bbp[2], zq, 16384);
    // vector quantize (in-place on zq, accumulates sse + histogram)
    vq_kernel<<<NTOK / 32, 256, 0, stream>>>(zq, cb, cbn, acc);
    // decoder
    liquid_gemm<256, 128, 128, 32, 1><<<dim3(128, 32, 1), 256, 0, stream>>>(zq, wsW, bbp[3], h1, 49152);
    liquid_gemm<128,  64,  64, 64, 1><<<dim3(64, 32, 1), 256, 0, stream>>>(h1, wsW, bbp[4], h0, 81920);
    liquid_gemm< 64, 128, 128, 64, 2><<<dim3(64, 32, 1), 256, 0, stream>>>(h0, wsW, bbp[5], h1, 90112);
    // scalars
    finalize_kernel<<<1, 512, 0, stream>>>(acc, scal);
}

// Round 2
// 816.006 us; speedup vs baseline: 1.7429x; 1.7429x over previous
//
#include <hip/hip_runtime.h>
#include <hip/hip_bf16.h>
#include <math.h>

#define B_N 32
#define S_LEN 4096
#define NTOK (B_N * S_LEN)   // 131072
#define EMB 256
#define NCODE 512
#define WB_STRIDE 98304      // per-batch weight entries (bf16)

typedef __attribute__((ext_vector_type(8))) short short8v;   // 8 bf16 = 4 VGPRs
typedef __attribute__((ext_vector_type(4))) float float4v;

__device__ inline ushort f2b(float v) {
    union { __hip_bfloat16 h; ushort u; } cv;
    cv.h = __float2bfloat16(v);   // RNE, matches XLA
    return cv.u;
}

// ---- ws layout (bytes) ----
constexpr size_t WSB_W   = 0;         // ushort[3145728] generated weights (bf16)
constexpr size_t WSB_CB  = 6291456;   // ushort[131072] codebook bf16
constexpr size_t WSB_CBN = 6553600;   // float[512] codebook sq-norms
constexpr size_t WSB_ACC = 6555648;   // float[513]: [0]=sse, [1..512]=hist
constexpr size_t WSB_H0  = 6557760;   // ushort[8388608] h0 / h4 (16B aligned)

// ---- out layout (floats) ----
constexpr size_t OUT_SCAL = 33554432; // loss, perplexity
constexpr size_t OUT_XR   = 33554434; // x_recon slot (also hosts h1/h3 bf16)
// h1/h3 bf16 buffer at byte offset 134217744 = (OUT_XR+2)*4  (16B aligned)

// ================= weight generation (fp32 math, bf16 out) =================
__global__ __launch_bounds__(256)
void wgen_kernel(const float* __restrict__ bw, const float* __restrict__ aw,
                 const float* __restrict__ ab, const float* __restrict__ adapt,
                 ushort* __restrict__ wout, int rows, int loff)
{
    __shared__ float ad[B_N * 64];
    int tid = threadIdx.x;
    for (int i = tid; i < B_N * 64; i += 256) ad[i] = adapt[i];
    __syncthreads();
    int r = blockIdx.x * 256 + tid;
    if (r >= rows) return;
    float a[64];
    const float4* aw4 = reinterpret_cast<const float4*>(aw + (size_t)r * 64);
#pragma unroll
    for (int q = 0; q < 16; ++q) {
        float4 v = aw4[q];
        a[4*q] = v.x; a[4*q+1] = v.y; a[4*q+2] = v.z; a[4*q+3] = v.w;
    }
    float abr = ab[r], bwr = bw[r];
    for (int b2 = 0; b2 < B_N; ++b2) {
        const float* adp = &ad[b2 * 64];
        float s0 = 0.f, s1 = 0.f, s2 = 0.f, s3 = 0.f;
#pragma unroll
        for (int j = 0; j < 64; j += 4) {
            s0 += a[j]   * adp[j];
            s1 += a[j+1] * adp[j+1];
            s2 += a[j+2] * adp[j+2];
            s3 += a[j+3] * adp[j+3];
        }
        float s = ((s0 + s1) + (s2 + s3)) + abr;
        wout[(size_t)b2 * WB_STRIDE + loff + r] = f2b(bwr + s);
    }
}

// ================= codebook prep: norms (fp32) + bf16 copy =================
__global__ __launch_bounds__(256)
void cbprep_kernel(const float* __restrict__ cb, float* __restrict__ cbn,
                   ushort* __restrict__ cbbf)
{
    int c = blockIdx.x * 256 + threadIdx.x;
    if (c >= NCODE) return;
    const float4* c4 = reinterpret_cast<const float4*>(cb) + (size_t)c * 64;
    ushort4* o4 = reinterpret_cast<ushort4*>(cbbf) + (size_t)c * 64;
    float s = 0.f;
#pragma unroll 8
    for (int q = 0; q < 64; ++q) {
        float4 v = c4[q];
        s += v.x*v.x + v.y*v.y + v.z*v.z + v.w*v.w;
        o4[q] = make_ushort4(f2b(v.x), f2b(v.y), f2b(v.z), f2b(v.w));
    }
    cbn[c] = s;
}

// ================= MFMA liquid linear =================
// 64 tok x 64 out per block, 4 waves, each 32x32 via 2x2 16x16x32 bf16 frags.
// SRC_F32: input fp32 (convert during staging) else bf16.
// DST_F32: output fp32 else bf16.  ACT: 0 none, 1 relu, 2 sigmoid.
template<int IN_F, int OUT_F, int SRC_F32, int ACT, int DST_F32>
__global__ __launch_bounds__(256)
void mfma_gemm(const void* __restrict__ xg, const ushort* __restrict__ wbf,
               const float* __restrict__ bbp, void* __restrict__ yg, int loff)
{
    constexpr int TS = 64, OT = 64;
    constexpr int LDA = IN_F + 8;            // pad: stride_dw % 32 == 4 -> conflict-free b128
    constexpr int KC  = (IN_F > 128) ? 128 : IN_F;
    constexpr int NKC = IN_F / KC;
    constexpr int LDB = KC + 8;

    __shared__ ushort aT[TS * LDA];
    __shared__ ushort bT[OT * LDB];

    const int tid = threadIdx.x;
    const int b   = blockIdx.y;
    const int s0  = blockIdx.x * TS;
    const int otb = blockIdx.z * OT;
    const size_t tokbase = (size_t)b * S_LEN + s0;

    // ---- stage A (full IN_F) ----
    if (SRC_F32) {
        const float4* xg4 = reinterpret_cast<const float4*>(xg) + tokbase * (IN_F/4);
#pragma unroll
        for (int it = 0; it < TS*IN_F/4/256; ++it) {
            int idx = tid + it*256;
            int t = idx / (IN_F/4), k4 = idx % (IN_F/4);
            float4 v = xg4[(size_t)t * (IN_F/4) + k4];
            *reinterpret_cast<ushort4*>(&aT[t*LDA + 4*k4]) =
                make_ushort4(f2b(v.x), f2b(v.y), f2b(v.z), f2b(v.w));
        }
    } else {
        const int4* xg4 = reinterpret_cast<const int4*>(
            reinterpret_cast<const ushort*>(xg) + tokbase * IN_F);
#pragma unroll
        for (int it = 0; it < TS*IN_F/8/256; ++it) {
            int idx = tid + it*256;
            int t = idx / (IN_F/8), k8 = idx % (IN_F/8);
            int4 v = xg4[(size_t)t * (IN_F/8) + k8];
            *reinterpret_cast<int4*>(&aT[t*LDA + 8*k8]) = v;
        }
    }

    const int lane  = tid & 63;
    const int w     = tid >> 6;
    const int t_off = (w & 1) * 32;
    const int n_off = (w >> 1) * 32;
    const int r16   = lane & 15;
    const int g     = lane >> 4;

    float4v acc[2][2];
#pragma unroll
    for (int i = 0; i < 2; ++i)
#pragma unroll
        for (int j = 0; j < 2; ++j) acc[i][j] = (float4v){0.f, 0.f, 0.f, 0.f};

    const int4* wb4 = reinterpret_cast<const int4*>(
        wbf + (size_t)b * WB_STRIDE + loff + (size_t)otb * IN_F);

    for (int kc = 0; kc < NKC; ++kc) {
        __syncthreads();
#pragma unroll
        for (int it = 0; it < OT*KC/8/256; ++it) {
            int idx = tid + it*256;
            int o = idx / (KC/8), k8 = idx % (KC/8);
            int4 v = wb4[((size_t)o * IN_F + kc*KC) / 8 + k8];
            *reinterpret_cast<int4*>(&bT[o*LDB + 8*k8]) = v;
        }
        __syncthreads();
#pragma unroll
        for (int ks = 0; ks < KC/32; ++ks) {
            const int ak = kc*KC + ks*32 + g*8;
            const int bk = ks*32 + g*8;
            short8v a0 = *reinterpret_cast<const short8v*>(&aT[(t_off      + r16)*LDA + ak]);
            short8v a1 = *reinterpret_cast<const short8v*>(&aT[(t_off + 16 + r16)*LDA + ak]);
            short8v b0 = *reinterpret_cast<const short8v*>(&bT[(n_off      + r16)*LDB + bk]);
            short8v b1 = *reinterpret_cast<const short8v*>(&bT[(n_off + 16 + r16)*LDB + bk]);
            acc[0][0] = __builtin_amdgcn_mfma_f32_16x16x32_bf16(a0, b0, acc[0][0], 0, 0, 0);
            acc[0][1] = __builtin_amdgcn_mfma_f32_16x16x32_bf16(a0, b1, acc[0][1], 0, 0, 0);
            acc[1][0] = __builtin_amdgcn_mfma_f32_16x16x32_bf16(a1, b0, acc[1][0], 0, 0, 0);
            acc[1][1] = __builtin_amdgcn_mfma_f32_16x16x32_bf16(a1, b1, acc[1][1], 0, 0, 0);
        }
    }

    // ---- epilogue ----
    float bias0 = bbp[otb + n_off + r16];
    float bias1 = bbp[otb + n_off + 16 + r16];
#pragma unroll
    for (int mi = 0; mi < 2; ++mi) {
#pragma unroll
        for (int ni = 0; ni < 2; ++ni) {
#pragma unroll
            for (int reg = 0; reg < 4; ++reg) {
                size_t trow = tokbase + t_off + mi*16 + g*4 + reg;
                int col = otb + n_off + ni*16 + r16;
                float v = acc[mi][ni][reg] + (ni ? bias1 : bias0);
                if (ACT == 1)      v = fmaxf(v, 0.f);
                else if (ACT == 2) v = 1.0f / (1.0f + expf(-v));
                if (DST_F32)
                    reinterpret_cast<float*>(yg)[trow * OUT_F + col] = v;
                else
                    reinterpret_cast<ushort*>(yg)[trow * OUT_F + col] = f2b(v);
            }
        }
    }
}

// ================= MFMA vector quantize (in-place on fp32 z) =================
// argmin over dist' = ||e||^2_fp32 - 2*(z.e)_bf16  (||z||^2 dropped: token-const)
__global__ __launch_bounds__(256)
void vq_mfma(float* __restrict__ z, const ushort* __restrict__ cbbf,
             const float* __restrict__ cbf, const float* __restrict__ cbn,
             float* __restrict__ acc_g)
{
    constexpr int LDZ = EMB + 8;   // 264
    __shared__ ushort zT[64 * LDZ];
    __shared__ ushort cbT[32 * LDZ];
    __shared__ float scbn[NCODE];
    __shared__ int   midx[64];
    __shared__ float red[256];

    const int tid  = threadIdx.x;
    const int tok0 = blockIdx.x * 64;

    // stage z (fp32 -> bf16)
    const float4* z4 = reinterpret_cast<const float4*>(z) + (size_t)tok0 * 64;
#pragma unroll
    for (int it = 0; it < 16; ++it) {
        int idx = tid + it*256;
        int t = idx >> 6, k4 = idx & 63;
        float4 v = z4[(size_t)t*64 + k4];
        *reinterpret_cast<ushort4*>(&zT[t*LDZ + 4*k4]) =
            make_ushort4(f2b(v.x), f2b(v.y), f2b(v.z), f2b(v.w));
    }
    for (int i = tid; i < NCODE; i += 256) scbn[i] = cbn[i];

    const int lane = tid & 63;
    const int w    = tid >> 6;
    const int r16  = lane & 15, g = lane >> 4;
    const int trow = w * 16;    // wave owns 16 tokens

    float mv[4] = {1e30f, 1e30f, 1e30f, 1e30f};
    int   mi[4] = {0, 0, 0, 0};

    for (int cblk = 0; cblk < 16; ++cblk) {
        __syncthreads();
        const int4* cb4 = reinterpret_cast<const int4*>(cbbf + (size_t)cblk * 32 * EMB);
#pragma unroll
        for (int it = 0; it < 4; ++it) {
            int idx = tid + it*256;
            int c = idx >> 5, k8 = idx & 31;
            int4 v = cb4[(size_t)c*32 + k8];
            *reinterpret_cast<int4*>(&cbT[c*LDZ + 8*k8]) = v;
        }
        __syncthreads();
        float4v d0 = (float4v){0.f,0.f,0.f,0.f};
        float4v d1 = (float4v){0.f,0.f,0.f,0.f};
#pragma unroll
        for (int ks = 0; ks < 8; ++ks) {
            const int kk = ks*32 + g*8;
            short8v a  = *reinterpret_cast<const short8v*>(&zT[(trow + r16)*LDZ + kk]);
            short8v b0 = *reinterpret_cast<const short8v*>(&cbT[r16*LDZ + kk]);
            short8v b1 = *reinterpret_cast<const short8v*>(&cbT[(16 + r16)*LDZ + kk]);
            d0 = __builtin_amdgcn_mfma_f32_16x16x32_bf16(a, b0, d0, 0, 0, 0);
            d1 = __builtin_amdgcn_mfma_f32_16x16x32_bf16(a, b1, d1, 0, 0, 0);
        }
        int c0 = cblk*32 + r16;            // D col = lane&15
        float cn0 = scbn[c0], cn1 = scbn[c0 + 16];
#pragma unroll
        for (int reg = 0; reg < 4; ++reg) {
            float dd0 = cn0 - 2.0f * d0[reg];
            if (dd0 < mv[reg]) { mv[reg] = dd0; mi[reg] = c0; }
            float dd1 = cn1 - 2.0f * d1[reg];
            if (dd1 < mv[reg]) { mv[reg] = dd1; mi[reg] = c0 + 16; }
        }
    }
    // butterfly over the 16 code-lanes; lex (val, idx) min == first-index argmin
#pragma unroll
    for (int m = 1; m <= 8; m <<= 1) {
#pragma unroll
        for (int reg = 0; reg < 4; ++reg) {
            float ov = __shfl_xor(mv[reg], m);
            int   oi = __shfl_xor(mi[reg], m);
            if (ov < mv[reg] || (ov == mv[reg] && oi < mi[reg])) {
                mv[reg] = ov; mi[reg] = oi;
            }
        }
    }
    if (r16 == 0) {
#pragma unroll
        for (int reg = 0; reg < 4; ++reg) midx[trow + g*4 + reg] = mi[reg];
    }
    __syncthreads();
    if (tid < 64) atomicAdd(&acc_g[1 + midx[tid]], 1.0f);

    // epilogue: out = z + (q - z) with true fp32 z (in-place), sse accumulate
    float lsse = 0.f;
    float4* zio = reinterpret_cast<float4*>(z) + (size_t)tok0 * 64;
    const float4* cf4 = reinterpret_cast<const float4*>(cbf);
#pragma unroll
    for (int it = 0; it < 16; ++it) {
        int idx = tid + it*256;
        int t = idx >> 6, k4 = idx & 63;
        float4 zv = zio[(size_t)t*64 + k4];
        float4 qv = cf4[(size_t)midx[t]*64 + k4];
        float dx = qv.x - zv.x, dy = qv.y - zv.y, dz = qv.z - zv.z, dw = qv.w - zv.w;
        lsse += dx*dx + dy*dy + dz*dz + dw*dw;
        zio[(size_t)t*64 + k4] = make_float4(zv.x + dx, zv.y + dy, zv.z + dz, zv.w + dw);
    }
    red[tid] = lsse;
    __syncthreads();
    for (int s = 128; s > 0; s >>= 1) {
        if (tid < s) red[tid] += red[tid + s];
        __syncthreads();
    }
    if (tid == 0) atomicAdd(&acc_g[0], red[0]);
}

// ================= finalize scalars =================
__global__ __launch_bounds__(512)
void finalize_kernel(const float* __restrict__ acc, float* __restrict__ out_scal)
{
    __shared__ float red[512];
    int tid = threadIdx.x;
    float p = acc[1 + tid] * (1.0f / (float)NTOK);
    red[tid] = p * logf(p + 1e-10f);
    __syncthreads();
    for (int s = 256; s > 0; s >>= 1) {
        if (tid < s) red[tid] += red[tid + s];
        __syncthreads();
    }
    if (tid == 0) {
        out_scal[0] = 1.25f * (acc[0] * (1.0f / 33554432.0f)); // q_latent + 0.25*e_latent
        out_scal[1] = expf(-red[0]);
    }
}

// ================= launch =================
extern "C" void kernel_launch(void* const* d_in, const int* in_sizes, int n_in,
                              void* d_out, int out_size, void* d_ws, size_t ws_size,
                              hipStream_t stream)
{
    (void)in_sizes; (void)n_in; (void)out_size; (void)ws_size;
    const float* x     = (const float*)d_in[0];
    const float* adapt = (const float*)d_in[1];
    const float* bw[6]  = {(const float*)d_in[2],  (const float*)d_in[6],  (const float*)d_in[10],
                           (const float*)d_in[14], (const float*)d_in[18], (const float*)d_in[22]};
    const float* bbp[6] = {(const float*)d_in[3],  (const float*)d_in[7],  (const float*)d_in[11],
                           (const float*)d_in[15], (const float*)d_in[19], (const float*)d_in[23]};
    const float* aw[6]  = {(const float*)d_in[4],  (const float*)d_in[8],  (const float*)d_in[12],
                           (const float*)d_in[16], (const float*)d_in[20], (const float*)d_in[24]};
    const float* ab[6]  = {(const float*)d_in[5],  (const float*)d_in[9],  (const float*)d_in[13],
                           (const float*)d_in[17], (const float*)d_in[21], (const float*)d_in[25]};
    const float* cb = (const float*)d_in[26];

    char*   wsb  = (char*)d_ws;
    ushort* wbf  = (ushort*)(wsb + WSB_W);
    ushort* cbbf = (ushort*)(wsb + WSB_CB);
    float*  cbn  = (float*) (wsb + WSB_CBN);
    float*  acc  = (float*) (wsb + WSB_ACC);
    ushort* h0   = (ushort*)(wsb + WSB_H0);            // h0 / h4 bf16

    float*  out  = (float*)d_out;
    float*  zf   = out;                                 // z_e fp32 -> z_q fp32 in place
    float*  scal = out + OUT_SCAL;
    float*  xr   = out + OUT_XR;                        // x_recon fp32
    ushort* h1   = (ushort*)((char*)d_out + 134217744); // h1 / h3 bf16 (16B aligned)

    hipMemsetAsync(acc, 0, 513 * sizeof(float), stream);

    const int rows[6] = {8192, 8192, 32768, 32768, 8192, 8192};
    const int loff[6] = {0, 8192, 16384, 49152, 81920, 90112};
    for (int l = 0; l < 6; ++l)
        wgen_kernel<<<rows[l] / 256, 256, 0, stream>>>(bw[l], aw[l], ab[l], adapt,
                                                       wbf, rows[l], loff[l]);
    cbprep_kernel<<<2, 256, 0, stream>>>(cb, cbn, cbbf);

    // encoder
    mfma_gemm<128,  64, 1, 1, 0><<<dim3(64, 32, 1), 256, 0, stream>>>(x,  wbf, bbp[0], h0, loff[0]);
    mfma_gemm< 64, 128, 0, 1, 0><<<dim3(64, 32, 2), 256, 0, stream>>>(h0, wbf, bbp[1], h1, loff[1]);
    mfma_gemm<128, 256, 0, 0, 1><<<dim3(64, 32, 4), 256, 0, stream>>>(h1, wbf, bbp[2], zf, loff[2]);
    // vector quantize (in-place, fp32 z slot)
    vq_mfma<<<NTOK / 64, 256, 0, stream>>>(zf, cbbf, cb, cbn, acc);
    // decoder
    mfma_gemm<256, 128, 1, 1, 0><<<dim3(64, 32, 2), 256, 0, stream>>>(zf, wbf, bbp[3], h1, loff[3]);
    mfma_gemm<128,  64, 0, 1, 0><<<dim3(64, 32, 1), 256, 0, stream>>>(h1, wbf, bbp[4], h0, loff[4]);
    mfma_gemm< 64, 128, 0, 2, 1><<<dim3(64, 32, 2), 256, 0, stream>>>(h0, wbf, bbp[5], xr, loff[5]);
    // scalars
    finalize_kernel<<<1, 512, 0, stream>>>(acc, scal);
}

// Round 3
// 602.605 us; speedup vs baseline: 2.3602x; 1.3541x over previous
//
#include <hip/hip_runtime.h>
#include <hip/hip_bf16.h>
#include <math.h>

#define B_N 32
#define S_LEN 4096
#define NTOK (B_N * S_LEN)   // 131072
#define EMB 256
#define NCODE 512
#define WB_STRIDE 98304      // per-batch weight entries (bf16)

typedef __attribute__((ext_vector_type(8))) short short8v;   // 8 bf16 = 4 VGPRs
typedef __attribute__((ext_vector_type(4))) float float4v;

__device__ inline ushort f2b(float v) {
    union { __hip_bfloat16 h; ushort u; } cv;
    cv.h = __float2bfloat16(v);   // RNE
    return cv.u;
}
__device__ inline float b2f(ushort u) {
    union { ushort u2[2]; float f; } cv;
    cv.u2[0] = 0; cv.u2[1] = u;
    return cv.f;
}

// ---- ws layout (bytes) ----
constexpr size_t WSB_W   = 0;         // ushort[3145728] generated weights (bf16)
constexpr size_t WSB_CB  = 6291456;   // ushort[131072] codebook bf16
constexpr size_t WSB_CBN = 6553600;   // float[512] codebook sq-norms
constexpr size_t WSB_ACC = 6555648;   // float[513]: [0]=sse, [1..512]=hist
constexpr size_t WSB_IDX = 6558720;   // int[131072] per-token code index

// ---- out layout (floats) ----
constexpr size_t OUT_SCAL = 33554432; // loss, perplexity
constexpr size_t OUT_XR   = 33554434; // x_recon (8B-aligned only -> float2 stores)

// ================= weight generation (all 6 layers, one launch) =================
struct WgenP {
    const float* bw[6]; const float* aw[6]; const float* ab[6];
    int loff[6]; int bstart[7];
};

__global__ __launch_bounds__(256)
void wgen_all(WgenP p, const float* __restrict__ adapt, ushort* __restrict__ wout)
{
    __shared__ float ad[B_N * 64];
    int tid = threadIdx.x;
    for (int i = tid; i < B_N * 64; i += 256) ad[i] = adapt[i];
    __syncthreads();
    int blk = blockIdx.x;
    int l = 0;
    while (l < 5 && blk >= p.bstart[l + 1]) ++l;
    int r = (blk - p.bstart[l]) * 256 + tid;

    float a[64];
    const float4* aw4 = reinterpret_cast<const float4*>(p.aw[l] + (size_t)r * 64);
#pragma unroll
    for (int q = 0; q < 16; ++q) {
        float4 v = aw4[q];
        a[4*q] = v.x; a[4*q+1] = v.y; a[4*q+2] = v.z; a[4*q+3] = v.w;
    }
    float abr = p.ab[l][r], bwr = p.bw[l][r];
    int loff = p.loff[l];
    for (int b2 = 0; b2 < B_N; ++b2) {
        const float* adp = &ad[b2 * 64];
        float s0 = 0.f, s1 = 0.f, s2 = 0.f, s3 = 0.f;
#pragma unroll
        for (int j = 0; j < 64; j += 4) {
            s0 += a[j]   * adp[j];
            s1 += a[j+1] * adp[j+1];
            s2 += a[j+2] * adp[j+2];
            s3 += a[j+3] * adp[j+3];
        }
        float s = ((s0 + s1) + (s2 + s3)) + abr;
        wout[(size_t)b2 * WB_STRIDE + loff + r] = f2b(bwr + s);
    }
}

// ================= codebook prep: norms (fp32) + bf16 copy =================
__global__ __launch_bounds__(256)
void cbprep_kernel(const float* __restrict__ cb, float* __restrict__ cbn,
                   ushort* __restrict__ cbbf)
{
    int c = blockIdx.x * 256 + threadIdx.x;
    if (c >= NCODE) return;
    const float4* c4 = reinterpret_cast<const float4*>(cb) + (size_t)c * 64;
    ushort4* o4 = reinterpret_cast<ushort4*>(cbbf) + (size_t)c * 64;
    float s = 0.f;
#pragma unroll 8
    for (int q = 0; q < 64; ++q) {
        float4 v = c4[q];
        s += v.x*v.x + v.y*v.y + v.z*v.z + v.w*v.w;
        o4[q] = make_ushort4(f2b(v.x), f2b(v.y), f2b(v.z), f2b(v.w));
    }
    cbn[c] = s;
}

// ================= fused encoder + VQ =================
// 64 tokens/block, 4 waves. Waves split output features per layer (weights
// read directly from L2). Intermediates live in LDS bf16.  Barriers: 4 + 16.
__global__ __launch_bounds__(256)
void enc_vq(const float* __restrict__ x, const ushort* __restrict__ wbf,
            const float* __restrict__ bb0, const float* __restrict__ bb1,
            const float* __restrict__ bb2,
            const ushort* __restrict__ cbbf, const float* __restrict__ cbf,
            const float* __restrict__ cbn,
            float* __restrict__ zq, int* __restrict__ idxg, float* __restrict__ accg)
{
    __shared__ __align__(16) ushort zbuf[64 * 264];   // z bf16 [64][264]
    __shared__ __align__(16) ushort regA[16896];      // xbuf[64][136] -> h1[64][136] -> cbuf[64][264]
    __shared__ __align__(16) ushort regB[64 * 72];    // h0 [64][72]
    __shared__ float scbn[NCODE];
    __shared__ int   midx[64];
    __shared__ float red[256];

    const int tid = threadIdx.x;
    const int b = blockIdx.y, s0 = blockIdx.x * 64;
    const size_t tok0 = (size_t)b * S_LEN + s0;
    const int lane = tid & 63, w = tid >> 6, r16 = lane & 15, g = lane >> 4;

    for (int i = tid; i < NCODE; i += 256) scbn[i] = cbn[i];

    { // stage x fp32 -> bf16 LDS [64][136]
        const float4* x4 = reinterpret_cast<const float4*>(x) + tok0 * 32;
#pragma unroll
        for (int it = 0; it < 8; ++it) {
            int idx = tid + it * 256;
            int t = idx >> 5, k4 = idx & 31;
            float4 v = x4[(size_t)t * 32 + k4];
            *reinterpret_cast<ushort4*>(&regA[t * 136 + 4 * k4]) =
                make_ushort4(f2b(v.x), f2b(v.y), f2b(v.z), f2b(v.w));
        }
    }
    __syncthreads();

    const ushort* wb = wbf + (size_t)b * WB_STRIDE;

    // ---- e0: 128 -> 64, relu; wave owns cols [w*16, w*16+16)
    {
        const ushort* w0 = wb;                       // loff 0
        short8v bf[4];
#pragma unroll
        for (int ks = 0; ks < 4; ++ks)
            bf[ks] = *reinterpret_cast<const short8v*>(
                w0 + (size_t)(w*16 + r16) * 128 + ks*32 + g*8);
        float bias = bb0[w*16 + r16];
#pragma unroll
        for (int tt = 0; tt < 4; ++tt) {
            float4v acc = (float4v){0.f, 0.f, 0.f, 0.f};
#pragma unroll
            for (int ks = 0; ks < 4; ++ks) {
                short8v a = *reinterpret_cast<const short8v*>(
                    &regA[(tt*16 + r16) * 136 + ks*32 + g*8]);
                acc = __builtin_amdgcn_mfma_f32_16x16x32_bf16(a, bf[ks], acc, 0, 0, 0);
            }
#pragma unroll
            for (int reg = 0; reg < 4; ++reg)
                regB[(tt*16 + g*4 + reg) * 72 + w*16 + r16] =
                    f2b(fmaxf(acc[reg] + bias, 0.f));
        }
    }
    __syncthreads();

    // ---- e1: 64 -> 128, relu; wave cols [w*32, +32); h1 -> regA[0..8704)
    {
        const ushort* w1 = wb + 8192;
#pragma unroll
        for (int nt = 0; nt < 2; ++nt) {
            int col0 = w*32 + nt*16;
            float bias = bb1[col0 + r16];
            short8v bf[2];
#pragma unroll
            for (int ks = 0; ks < 2; ++ks)
                bf[ks] = *reinterpret_cast<const short8v*>(
                    w1 + (size_t)(col0 + r16) * 64 + ks*32 + g*8);
#pragma unroll
            for (int tt = 0; tt < 4; ++tt) {
                float4v acc = (float4v){0.f, 0.f, 0.f, 0.f};
#pragma unroll
                for (int ks = 0; ks < 2; ++ks) {
                    short8v a = *reinterpret_cast<const short8v*>(
                        &regB[(tt*16 + r16) * 72 + ks*32 + g*8]);
                    acc = __builtin_amdgcn_mfma_f32_16x16x32_bf16(a, bf[ks], acc, 0, 0, 0);
                }
#pragma unroll
                for (int reg = 0; reg < 4; ++reg)
                    regA[(tt*16 + g*4 + reg) * 136 + col0 + r16] =
                        f2b(fmaxf(acc[reg] + bias, 0.f));
            }
        }
    }
    __syncthreads();

    // ---- e2: 128 -> 256, none; wave cols [w*64, +64); z -> zbuf bf16
    {
        const ushort* w2 = wb + 16384;
#pragma unroll
        for (int nt = 0; nt < 4; ++nt) {
            int col0 = w*64 + nt*16;
            float bias = bb2[col0 + r16];
            short8v bf[4];
#pragma unroll
            for (int ks = 0; ks < 4; ++ks)
                bf[ks] = *reinterpret_cast<const short8v*>(
                    w2 + (size_t)(col0 + r16) * 128 + ks*32 + g*8);
#pragma unroll
            for (int tt = 0; tt < 4; ++tt) {
                float4v acc = (float4v){0.f, 0.f, 0.f, 0.f};
#pragma unroll
                for (int ks = 0; ks < 4; ++ks) {
                    short8v a = *reinterpret_cast<const short8v*>(
                        &regA[(tt*16 + r16) * 136 + ks*32 + g*8]);
                    acc = __builtin_amdgcn_mfma_f32_16x16x32_bf16(a, bf[ks], acc, 0, 0, 0);
                }
#pragma unroll
                for (int reg = 0; reg < 4; ++reg)
                    zbuf[(tt*16 + g*4 + reg) * 264 + col0 + r16] = f2b(acc[reg] + bias);
            }
        }
    }
    __syncthreads();   // zbuf complete; regA free for codebook chunks

    // ---- VQ: wave owns tokens [w*16, +16); argmin over 512 codes
    short8v az[8];
#pragma unroll
    for (int ks = 0; ks < 8; ++ks)
        az[ks] = *reinterpret_cast<const short8v*>(
            &zbuf[(w*16 + r16) * 264 + ks*32 + g*8]);

    float mv[4] = {1e30f, 1e30f, 1e30f, 1e30f};
    int   mi[4] = {0, 0, 0, 0};
    const int4* cb4 = reinterpret_cast<const int4*>(cbbf);

    for (int ch = 0; ch < 8; ++ch) {
        __syncthreads();
#pragma unroll
        for (int it = 0; it < 8; ++it) {   // stage 64 codes x 256 k (bf16)
            int idx = tid + it * 256;
            int c = idx >> 5, k8 = idx & 31;
            reinterpret_cast<int4*>(regA)[c * 33 + k8] =
                cb4[(size_t)(ch*64 + c) * 32 + k8];
        }
        __syncthreads();
#pragma unroll
        for (int ct = 0; ct < 4; ++ct) {
            float4v d = (float4v){0.f, 0.f, 0.f, 0.f};
#pragma unroll
            for (int ks = 0; ks < 8; ++ks) {
                short8v bfr = *reinterpret_cast<const short8v*>(
                    &regA[(ct*16 + r16) * 264 + ks*32 + g*8]);
                d = __builtin_amdgcn_mfma_f32_16x16x32_bf16(az[ks], bfr, d, 0, 0, 0);
            }
            int c0 = ch*64 + ct*16 + r16;   // D col = lane&15
            float cn = scbn[c0];
#pragma unroll
            for (int reg = 0; reg < 4; ++reg) {
                float dd = cn - 2.0f * d[reg];
                if (dd < mv[reg]) { mv[reg] = dd; mi[reg] = c0; }
            }
        }
    }
    // butterfly over 16 code-lanes; lex (val, idx) min == first-index argmin
#pragma unroll
    for (int m = 1; m <= 8; m <<= 1) {
#pragma unroll
        for (int reg = 0; reg < 4; ++reg) {
            float ov = __shfl_xor(mv[reg], m);
            int   oi = __shfl_xor(mi[reg], m);
            if (ov < mv[reg] || (ov == mv[reg] && oi < mi[reg])) {
                mv[reg] = ov; mi[reg] = oi;
            }
        }
    }
    if (r16 == 0) {
#pragma unroll
        for (int reg = 0; reg < 4; ++reg) midx[w*16 + g*4 + reg] = mi[reg];
    }
    __syncthreads();
    if (tid < 64) {
        idxg[tok0 + tid] = midx[tid];
        atomicAdd(&accg[1 + midx[tid]], 1.0f);
    }

    // ---- epilogue: z_q = z + (q - z) (z from bf16 zbuf), sse accumulate
    float lsse = 0.f;
    float4* zq4 = reinterpret_cast<float4*>(zq) + tok0 * 64;
    const float4* cf4 = reinterpret_cast<const float4*>(cbf);
#pragma unroll
    for (int it = 0; it < 16; ++it) {
        int idx = tid + it * 256;
        int t = idx >> 6, k4 = idx & 63;
        float4 q = cf4[(size_t)midx[t] * 64 + k4];
        ushort4 zb = *reinterpret_cast<const ushort4*>(&zbuf[t * 264 + 4 * k4]);
        float zx = b2f(zb.x), zy = b2f(zb.y), zz = b2f(zb.z), zw = b2f(zb.w);
        float dx = q.x - zx, dy = q.y - zy, dz = q.z - zz, dw = q.w - zw;
        lsse += dx*dx + dy*dy + dz*dz + dw*dw;
        zq4[(size_t)t * 64 + k4] = make_float4(zx + dx, zy + dy, zz + dz, zw + dw);
    }
    red[tid] = lsse;
    __syncthreads();
    for (int s = 128; s > 0; s >>= 1) {
        if (tid < s) red[tid] += red[tid + s];
        __syncthreads();
    }
    if (tid == 0) atomicAdd(&accg[0], red[0]);
}

// ================= fused decoder =================
// Reads per-token idx, gathers q rows (bf16, L2), d0->d1->d2 in LDS,
// vectorized x_recon stores.
__global__ __launch_bounds__(256)
void dec_fused(const int* __restrict__ idxg, const ushort* __restrict__ cbbf,
               const ushort* __restrict__ wbf,
               const float* __restrict__ bb3, const float* __restrict__ bb4,
               const float* __restrict__ bb5,
               float* __restrict__ xr)
{
    __shared__ __align__(16) ushort regA[16896];  // qbuf bf16 [64][264] -> xrbuf fp32 [64][132]
    __shared__ __align__(16) ushort regB[13312];  // h3 [64][136] @0, h4 [64][72] @8704
    __shared__ int midx[64];

    const int tid = threadIdx.x;
    const int b = blockIdx.y, s0 = blockIdx.x * 64;
    const size_t tok0 = (size_t)b * S_LEN + s0;
    const int lane = tid & 63, w = tid >> 6, r16 = lane & 15, g = lane >> 4;

    if (tid < 64) midx[tid] = idxg[tok0 + tid];
    __syncthreads();
    {   // gather q rows bf16 -> qbuf
        const int4* cb4 = reinterpret_cast<const int4*>(cbbf);
#pragma unroll
        for (int it = 0; it < 8; ++it) {
            int idx = tid + it * 256;
            int t = idx >> 5, k8 = idx & 31;
            reinterpret_cast<int4*>(regA)[t * 33 + k8] =
                cb4[(size_t)midx[t] * 32 + k8];
        }
    }
    __syncthreads();

    const ushort* wb = wbf + (size_t)b * WB_STRIDE;
    ushort* h3 = regB;
    ushort* h4 = regB + 8704;

    // d0: 256 -> 128, relu; wave cols [w*32, +32)
    {
        const ushort* wD = wb + 49152;
#pragma unroll
        for (int nt = 0; nt < 2; ++nt) {
            int col0 = w*32 + nt*16;
            float bias = bb3[col0 + r16];
            short8v bf[8];
#pragma unroll
            for (int ks = 0; ks < 8; ++ks)
                bf[ks] = *reinterpret_cast<const short8v*>(
                    wD + (size_t)(col0 + r16) * 256 + ks*32 + g*8);
#pragma unroll
            for (int tt = 0; tt < 4; ++tt) {
                float4v acc = (float4v){0.f, 0.f, 0.f, 0.f};
#pragma unroll
                for (int ks = 0; ks < 8; ++ks) {
                    short8v a = *reinterpret_cast<const short8v*>(
                        &regA[(tt*16 + r16) * 264 + ks*32 + g*8]);
                    acc = __builtin_amdgcn_mfma_f32_16x16x32_bf16(a, bf[ks], acc, 0, 0, 0);
                }
#pragma unroll
                for (int reg = 0; reg < 4; ++reg)
                    h3[(tt*16 + g*4 + reg) * 136 + col0 + r16] =
                        f2b(fmaxf(acc[reg] + bias, 0.f));
            }
        }
    }
    __syncthreads();
    // d1: 128 -> 64, relu; wave cols [w*16, +16)
    {
        const ushort* wD = wb + 81920;
        float bias = bb4[w*16 + r16];
        short8v bf[4];
#pragma unroll
        for (int ks = 0; ks < 4; ++ks)
            bf[ks] = *reinterpret_cast<const short8v*>(
                wD + (size_t)(w*16 + r16) * 128 + ks*32 + g*8);
#pragma unroll
        for (int tt = 0; tt < 4; ++tt) {
            float4v acc = (float4v){0.f, 0.f, 0.f, 0.f};
#pragma unroll
            for (int ks = 0; ks < 4; ++ks) {
                short8v a = *reinterpret_cast<const short8v*>(
                    &h3[(tt*16 + r16) * 136 + ks*32 + g*8]);
                acc = __builtin_amdgcn_mfma_f32_16x16x32_bf16(a, bf[ks], acc, 0, 0, 0);
            }
#pragma unroll
            for (int reg = 0; reg < 4; ++reg)
                h4[(tt*16 + g*4 + reg) * 72 + w*16 + r16] =
                    f2b(fmaxf(acc[reg] + bias, 0.f));
        }
    }
    __syncthreads();
    // d2: 64 -> 128, sigmoid; wave cols [w*32, +32); -> xrbuf fp32
    float* xrb = reinterpret_cast<float*>(regA);
    {
        const ushort* wD = wb + 90112;
#pragma unroll
        for (int nt = 0; nt < 2; ++nt) {
            int col0 = w*32 + nt*16;
            float bias = bb5[col0 + r16];
            short8v bf[2];
#pragma unroll
            for (int ks = 0; ks < 2; ++ks)
                bf[ks] = *reinterpret_cast<const short8v*>(
                    wD + (size_t)(col0 + r16) * 64 + ks*32 + g*8);
#pragma unroll
            for (int tt = 0; tt < 4; ++tt) {
                float4v acc = (float4v){0.f, 0.f, 0.f, 0.f};
#pragma unroll
                for (int ks = 0; ks < 2; ++ks) {
                    short8v a = *reinterpret_cast<const short8v*>(
                        &h4[(tt*16 + r16) * 72 + ks*32 + g*8]);
                    acc = __builtin_amdgcn_mfma_f32_16x16x32_bf16(a, bf[ks], acc, 0, 0, 0);
                }
#pragma unroll
                for (int reg = 0; reg < 4; ++reg) {
                    float v = acc[reg] + bias;
                    xrb[(tt*16 + g*4 + reg) * 132 + col0 + r16] =
                        1.0f / (1.0f + expf(-v));
                }
            }
        }
    }
    __syncthreads();
    {   // vectorized store (xr base only 8B-aligned -> float2)
        float2* xr2 = reinterpret_cast<float2*>(xr) + tok0 * 64;
#pragma unroll
        for (int it = 0; it < 16; ++it) {
            int idx = tid + it * 256;
            int t = idx >> 6, k2 = idx & 63;
            xr2[(size_t)t * 64 + k2] =
                make_float2(xrb[t * 132 + 2*k2], xrb[t * 132 + 2*k2 + 1]);
        }
    }
}

// ================= finalize scalars =================
__global__ __launch_bounds__(512)
void finalize_kernel(const float* __restrict__ acc, float* __restrict__ out_scal)
{
    __shared__ float red[512];
    int tid = threadIdx.x;
    float p = acc[1 + tid] * (1.0f / (float)NTOK);
    red[tid] = p * logf(p + 1e-10f);
    __syncthreads();
    for (int s = 256; s > 0; s >>= 1) {
        if (tid < s) red[tid] += red[tid + s];
        __syncthreads();
    }
    if (tid == 0) {
        out_scal[0] = 1.25f * (acc[0] * (1.0f / 33554432.0f)); // q_latent + 0.25*e_latent
        out_scal[1] = expf(-red[0]);
    }
}

// ================= launch =================
extern "C" void kernel_launch(void* const* d_in, const int* in_sizes, int n_in,
                              void* d_out, int out_size, void* d_ws, size_t ws_size,
                              hipStream_t stream)
{
    (void)in_sizes; (void)n_in; (void)out_size; (void)ws_size;
    const float* x     = (const float*)d_in[0];
    const float* adapt = (const float*)d_in[1];
    const float* bw[6]  = {(const float*)d_in[2],  (const float*)d_in[6],  (const float*)d_in[10],
                           (const float*)d_in[14], (const float*)d_in[18], (const float*)d_in[22]};
    const float* bbp[6] = {(const float*)d_in[3],  (const float*)d_in[7],  (const float*)d_in[11],
                           (const float*)d_in[15], (const float*)d_in[19], (const float*)d_in[23]};
    const float* aw[6]  = {(const float*)d_in[4],  (const float*)d_in[8],  (const float*)d_in[12],
                           (const float*)d_in[16], (const float*)d_in[20], (const float*)d_in[24]};
    const float* ab[6]  = {(const float*)d_in[5],  (const float*)d_in[9],  (const float*)d_in[13],
                           (const float*)d_in[17], (const float*)d_in[21], (const float*)d_in[25]};
    const float* cb = (const float*)d_in[26];

    char*   wsb  = (char*)d_ws;
    ushort* wbf  = (ushort*)(wsb + WSB_W);
    ushort* cbbf = (ushort*)(wsb + WSB_CB);
    float*  cbn  = (float*) (wsb + WSB_CBN);
    float*  acc  = (float*) (wsb + WSB_ACC);
    int*    idxg = (int*)   (wsb + WSB_IDX);

    float*  out  = (float*)d_out;
    float*  zf   = out;              // z_q fp32
    float*  scal = out + OUT_SCAL;
    float*  xr   = out + OUT_XR;     // x_recon fp32

    hipMemsetAsync(acc, 0, 513 * sizeof(float), stream);

    WgenP p;
    const int loff[6]   = {0, 8192, 16384, 49152, 81920, 90112};
    const int bstart[7] = {0, 32, 64, 192, 320, 352, 384};
    for (int l = 0; l < 6; ++l) {
        p.bw[l] = bw[l]; p.aw[l] = aw[l]; p.ab[l] = ab[l]; p.loff[l] = loff[l];
    }
    for (int i = 0; i < 7; ++i) p.bstart[i] = bstart[i];

    wgen_all<<<384, 256, 0, stream>>>(p, adapt, wbf);
    cbprep_kernel<<<2, 256, 0, stream>>>(cb, cbn, cbbf);
    enc_vq<<<dim3(64, 32), 256, 0, stream>>>(x, wbf, bbp[0], bbp[1], bbp[2],
                                             cbbf, cb, cbn, zf, idxg, acc);
    dec_fused<<<dim3(64, 32), 256, 0, stream>>>(idxg, cbbf, wbf,
                                                bbp[3], bbp[4], bbp[5], xr);
    finalize_kernel<<<1, 512, 0, stream>>>(acc, scal);
}